// Round 9
// baseline (691.936 us; speedup 1.0000x reference)
//
#include <hip/hip_runtime.h>
#include <math.h>

typedef unsigned short ushort;
typedef unsigned int uint;
typedef __attribute__((ext_vector_type(8))) short short8;
typedef __attribute__((ext_vector_type(4))) float f32x4;
typedef __attribute__((ext_vector_type(4))) ushort us4;

constexpr int BS = 2, C_IN = 8, CTX = 1024, TGT = 96;
constexpr int DM = 256, NH = 16, DFF = 1024, NL = 4;
constexpr int NF = 256, TOTAL = 320;
constexpr int NB = 16;
constexpr int DK = 16;
constexpr float EPS = 1e-5f;
constexpr float SCALE = 0.25f;
constexpr int KHEAD = DM * TOTAL;  // 81920
constexpr int M = NB * TOTAL;      // 5120

__device__ __forceinline__ ushort f2b(float x) {
    uint u = __float_as_uint(x);
    u += 0x7fff + ((u >> 16) & 1);
    return (ushort)(u >> 16);
}
__device__ __forceinline__ float bu2f(ushort x) { return __uint_as_float(((uint)x) << 16); }
__device__ __forceinline__ float lo2f(uint p) { return __uint_as_float(p << 16); }
__device__ __forceinline__ float hi2f(uint p) { return __uint_as_float(p & 0xffff0000u); }
__device__ __forceinline__ uint pack2(float a, float b) { return (uint)f2b(a) | ((uint)f2b(b) << 16); }

// ---------------- generic convert+transpose: src fp32 (R x C) -> dst bf16 (C x R) ----------------
__global__ void k_convt(const float* __restrict__ src, ushort* __restrict__ dst,
                        int R, int C, int sls, int dls) {
    __shared__ ushort tile[32][33];
    src += (size_t)blockIdx.z * sls;
    dst += (size_t)blockIdx.z * dls;
    int c0 = blockIdx.x * 32, r0 = blockIdx.y * 32;
    int tx = threadIdx.x, ty = threadIdx.y;
    tile[ty][tx] = f2b(src[(r0 + ty) * C + c0 + tx]);
    __syncthreads();
    dst[(c0 + ty) * R + r0 + tx] = tile[tx][ty];
}

// ---------------- all 16 square (256x256) weights in one launch ----------------
__global__ void k_convt_sq(const float* __restrict__ WQ, const float* __restrict__ WK,
                           const float* __restrict__ WV, const float* __restrict__ WO,
                           ushort* __restrict__ Wtqkv, ushort* __restrict__ WtO) {
    __shared__ ushort tile[32][33];
    int z = blockIdx.z, w = z >> 2, l = z & 3;
    const float* src = (w == 0 ? WQ : (w == 1 ? WK : (w == 2 ? WV : WO))) + l * 65536;
    ushort* dst = (w < 3) ? (Wtqkv + (size_t)l * 768 * 256 + w * 256 * 256)
                          : (WtO + (size_t)l * 65536);
    int c0 = blockIdx.x * 32, r0 = blockIdx.y * 32;
    int tx = threadIdx.x, ty = threadIdx.y;
    tile[ty][tx] = f2b(src[(r0 + ty) * 256 + c0 + tx]);
    __syncthreads();
    dst[(c0 + ty) * 256 + r0 + tx] = tile[tx][ty];
}

// ---------------- head weight permute: WhT2[t][p*256+d] = Wh[(d*320+p)*96 + t] ----------------
__global__ void k_convt_head(const float* __restrict__ Wh, ushort* __restrict__ WhT2) {
    __shared__ ushort tile[32][33];
    int t0 = blockIdx.x * 32, d0 = blockIdx.y * 32, p = blockIdx.z;
    int tx = threadIdx.x, ty = threadIdx.y;
    tile[ty][tx] = f2b(Wh[((size_t)(d0 + ty) * 320 + p) * 96 + t0 + tx]);
    __syncthreads();
    WhT2[(size_t)(t0 + ty) * KHEAD + p * 256 + d0 + tx] = tile[tx][ty];
}

// ---------------- RevIN ----------------
__global__ void k_revin(const float* __restrict__ z, const float* __restrict__ rw,
                        const float* __restrict__ rb, float* __restrict__ zn,
                        float* __restrict__ meanv, float* __restrict__ stdv) {
    int bc = blockIdx.x, t = threadIdx.x;
    __shared__ float r1[256], r2[256];
    float s1 = 0.f, s2 = 0.f;
    for (int i = t; i < CTX; i += 256) {
        float x = z[bc * CTX + i];
        s1 += x; s2 += x * x;
    }
    r1[t] = s1; r2[t] = s2; __syncthreads();
    for (int off = 128; off > 0; off >>= 1) {
        if (t < off) { r1[t] += r1[t + off]; r2[t] += r2[t + off]; }
        __syncthreads();
    }
    float m = r1[0] * (1.0f / CTX);
    float var = r2[0] * (1.0f / CTX) - m * m;
    float sd = sqrtf(var + EPS);
    float w = rw[bc % C_IN], b = rb[bc % C_IN];
    float inv = 1.0f / sd;
    for (int i = t; i < CTX; i += 256) {
        float x = z[bc * CTX + i];
        zn[bc * CTX + i] = (x - m) * inv * w + b;
    }
    if (t == 0) { meanv[bc] = m; stdv[bc] = sd; }
}

// ---------------- dual-scale patch embed + positional -> bf16 u ----------------
__global__ void k_embed(const float* __restrict__ zn, const float* __restrict__ Wf,
                        const float* __restrict__ bfv, const float* __restrict__ Wc,
                        const float* __restrict__ bcv, const float* __restrict__ Wpos,
                        ushort* __restrict__ u) {
    int bc = blockIdx.x / TOTAL, p = blockIdx.x % TOTAL, d = threadIdx.x;
    float acc;
    if (p < NF) {
        acc = bfv[d];
        int base = p * 4;
        for (int i = 0; i < 8; i++) {
            int idx = min(base + i, CTX - 1);
            acc += zn[bc * CTX + idx] * Wf[i * DM + d];
        }
    } else {
        int pc = p - NF;
        acc = bcv[d];
        int base = pc * 16;
        for (int i = 0; i < 32; i++) {
            int idx = min(base + i, CTX - 1);
            acc += zn[bc * CTX + idx] * Wc[i * DM + d];
        }
    }
    acc += Wpos[p * DM + d];
    u[(bc * TOTAL + p) * DM + d] = f2b(acc);
}

// ---------------- shared GEMM core: 64 rows x 256 cols per block, 4 waves, wave = 16x256 ----------------
// As[64][40], Bs[256][40]; Wt pre-offset to the 256-row N-slice (row-major N x K).
__device__ __forceinline__ void gemm_core(const ushort* __restrict__ A, const ushort* __restrict__ Wt,
                                          int K, int m0, ushort (*As)[40], ushort (*Bs)[40],
                                          f32x4* acc) {
    int tid = threadIdx.x;
    int wave = tid >> 6, lane = tid & 63, quad = lane >> 4, l16 = lane & 15;
    int row = tid >> 2, kc = (tid & 3) * 8;
    for (int k0 = 0; k0 < K; k0 += 32) {
        *(short8*)&As[row][kc] = *(const short8*)&A[(m0 + row) * K + k0 + kc];
#pragma unroll
        for (int i = 0; i < 4; i++)
            *(short8*)&Bs[i * 64 + row][kc] = *(const short8*)&Wt[(i * 64 + row) * K + k0 + kc];
        __syncthreads();
        short8 af = *(const short8*)&As[wave * 16 + l16][quad * 8];
#pragma unroll
        for (int nt = 0; nt < 16; nt++) {
            short8 bf = *(const short8*)&Bs[nt * 16 + l16][quad * 8];
            acc[nt] = __builtin_amdgcn_mfma_f32_16x16x32_bf16(af, bf, acc[nt], 0, 0, 0);
        }
        __syncthreads();
    }
}

// ---------------- QKV GEMM: grid (M/64, 3); N-slice = q/k/v ----------------
__global__ __launch_bounds__(256, 2) void k_gemm_qkv(const ushort* __restrict__ u,
                                                     const ushort* __restrict__ Wtl,
                                                     const float* __restrict__ bQ,
                                                     const float* __restrict__ bK,
                                                     const float* __restrict__ bV,
                                                     ushort* __restrict__ qkv) {
    __shared__ ushort As[64][40];
    __shared__ ushort Bs[256][40];
    int m0 = blockIdx.x * 64, sl = blockIdx.y;
    f32x4 acc[16];
#pragma unroll
    for (int nt = 0; nt < 16; nt++) acc[nt] = (f32x4){0.f, 0.f, 0.f, 0.f};
    gemm_core(u, Wtl + sl * 256 * 256, 256, m0, As, Bs, acc);
    int lane = threadIdx.x & 63, wave = threadIdx.x >> 6, quad = lane >> 4, l16 = lane & 15;
    const float* bias = sl == 0 ? bQ : (sl == 1 ? bK : bV);
    ushort* out = qkv + (size_t)sl * M * DM;
#pragma unroll
    for (int nt = 0; nt < 16; nt++) {
        int col = nt * 16 + l16;
        float bi = bias[col];
#pragma unroll
        for (int r = 0; r < 4; r++) {
            int rowm = m0 + wave * 16 + quad * 4 + r;
            out[rowm * DM + col] = f2b(acc[nt][r] + bi);
        }
    }
}

// ---------------- F1 GEMM + GELU: grid (M/64, 4) ----------------
__global__ __launch_bounds__(256, 2) void k_gemm_gelu(const ushort* __restrict__ u,
                                                      const ushort* __restrict__ Wtl,
                                                      const float* __restrict__ bias,
                                                      ushort* __restrict__ hbuf) {
    __shared__ ushort As[64][40];
    __shared__ ushort Bs[256][40];
    int m0 = blockIdx.x * 64, n0 = blockIdx.y * 256;
    f32x4 acc[16];
#pragma unroll
    for (int nt = 0; nt < 16; nt++) acc[nt] = (f32x4){0.f, 0.f, 0.f, 0.f};
    gemm_core(u, Wtl + (size_t)n0 * 256, 256, m0, As, Bs, acc);
    int lane = threadIdx.x & 63, wave = threadIdx.x >> 6, quad = lane >> 4, l16 = lane & 15;
#pragma unroll
    for (int nt = 0; nt < 16; nt++) {
        int col = nt * 16 + l16;
        float bi = bias[n0 + col];
#pragma unroll
        for (int r = 0; r < 4; r++) {
            int rowm = m0 + wave * 16 + quad * 4 + r;
            float vv = acc[nt][r] + bi;
            vv = vv * 0.5f * (1.0f + erff(vv * 0.70710678118f));
            hbuf[rowm * DFF + n0 + col] = f2b(vv);
        }
    }
}

// ---------------- GEMM + bias + residual + LayerNorm (in place on u): grid (M/64) ----------------
__global__ __launch_bounds__(256, 2) void k_gemm_ln(const ushort* __restrict__ A,
                                                    const ushort* __restrict__ Wtl,
                                                    const float* __restrict__ bias,
                                                    const float* __restrict__ ls,
                                                    const float* __restrict__ lb,
                                                    ushort* __restrict__ u, int K) {
    __shared__ ushort As[64][40];
    __shared__ ushort Bs[256][40];
    int m0 = blockIdx.x * 64;
    f32x4 acc[16];
#pragma unroll
    for (int nt = 0; nt < 16; nt++) acc[nt] = (f32x4){0.f, 0.f, 0.f, 0.f};
    gemm_core(A, Wtl, K, m0, As, Bs, acc);
    int lane = threadIdx.x & 63, wave = threadIdx.x >> 6, quad = lane >> 4, l16 = lane & 15;
#pragma unroll
    for (int r = 0; r < 4; r++) {
        int rowm = m0 + wave * 16 + quad * 4 + r;
        ushort* up = &u[rowm * DM];
        float xv[16];
        float s1 = 0.f, s2 = 0.f;
#pragma unroll
        for (int nt = 0; nt < 16; nt++) {
            int col = nt * 16 + l16;
            float x = acc[nt][r] + bias[col] + bu2f(up[col]);
            xv[nt] = x; s1 += x; s2 += x * x;
        }
        s1 += __shfl_xor(s1, 1); s2 += __shfl_xor(s2, 1);
        s1 += __shfl_xor(s1, 2); s2 += __shfl_xor(s2, 2);
        s1 += __shfl_xor(s1, 4); s2 += __shfl_xor(s2, 4);
        s1 += __shfl_xor(s1, 8); s2 += __shfl_xor(s2, 8);
        float m = s1 * (1.0f / DM);
        float var = s2 * (1.0f / DM) - m * m;
        float rs = rsqrtf(var + EPS);
#pragma unroll
        for (int nt = 0; nt < 16; nt++) {
            int col = nt * 16 + l16;
            up[col] = f2b((xv[nt] - m) * rs * ls[col] + lb[col]);
        }
    }
}

// ---------------- MFMA fused attention v4 (unchanged from R8) ----------------
__global__ __launch_bounds__(256, 4) void k_attn(const ushort* __restrict__ qm, const ushort* __restrict__ km,
                                                 const ushort* __restrict__ vm, uint4* __restrict__ sp,
                                                 ushort* __restrict__ ao, int mode) {
    __shared__ ushort sh[10240];
    uint* sh32 = (uint*)sh;
    int bh = blockIdx.x, b = bh >> 4, h = bh & 15;
    int i0 = blockIdx.y * 64;
    int t = threadIdx.x, wave = t >> 6, lane = t & 63, quad = lane >> 4, l16 = lane & 15;
    const short8 zero8 = (short8){0, 0, 0, 0, 0, 0, 0, 0};

    for (int idx = t; idx < 640; idx += 256) {
        int j = idx >> 1, half = idx & 1;
        short8 kv = *(const short8*)&km[(b * TOTAL + j) * DM + h * DK + half * 8];
        int jt = j >> 4, jl = j & 15;
        *(short8*)&sh[((jt * 2 + half) * 16 + jl) * 8] = kv;
    }
    for (int idx = t; idx < 320; idx += 256) {
        int jp = idx >> 1, dh = idx & 1;
        int j = jp * 2;
        uint4 a = *(const uint4*)&vm[(b * TOTAL + j) * DM + h * DK + dh * 8];
        uint4 bb = *(const uint4*)&vm[(b * TOTAL + j + 1) * DM + h * DK + dh * 8];
        const ushort* ap = (const ushort*)&a;
        const ushort* bp = (const ushort*)&bb;
        int jr = j & 31;
        int q = (jr & 15) >> 2, jj = ((jr >> 4) << 2) + (jr & 3);
        int base = 5120 + ((j >> 5) * 4 + q) * 128 + jj;
#pragma unroll
        for (int dd = 0; dd < 8; dd++) {
            int d = dh * 8 + dd;
            uint val = (uint)ap[dd] | ((uint)bp[dd] << 16);
            sh32[(base + d * 8) >> 1] = val;
        }
    }
    short8 qf = zero8;
    if (quad < 2) qf = *(const short8*)&qm[(b * TOTAL + i0 + wave * 16 + l16) * DM + h * DK + quad * 8];
    __syncthreads();

    f32x4 acc[20];
#pragma unroll
    for (int nt = 0; nt < 20; nt++) {
        short8 kf = *(const short8*)&sh[((nt * 2 + (quad & 1)) * 16 + l16) * 8];
        acc[nt] = __builtin_amdgcn_mfma_f32_16x16x32_bf16(kf, qf, (f32x4){0.f, 0.f, 0.f, 0.f}, 0, 0, 0);
    }

    int cb = (bh * 5 + (int)blockIdx.y) * 10 * 256 + t;
#pragma unroll
    for (int c = 0; c < 10; c++) {
        float e[8];
#pragma unroll
        for (int j = 0; j < 8; j++) e[j] = acc[2 * c + (j >> 2)][j & 3] * SCALE;
        if (mode) {
            uint4 pv = sp[cb + c * 256];
            e[0] += lo2f(pv.x); e[1] += hi2f(pv.x); e[2] += lo2f(pv.y); e[3] += hi2f(pv.y);
            e[4] += lo2f(pv.z); e[5] += hi2f(pv.z); e[6] += lo2f(pv.w); e[7] += hi2f(pv.w);
        }
        if (mode != 2) {
            uint4 ov;
            ov.x = pack2(e[0], e[1]); ov.y = pack2(e[2], e[3]);
            ov.z = pack2(e[4], e[5]); ov.w = pack2(e[6], e[7]);
            sp[cb + c * 256] = ov;
        }
#pragma unroll
        for (int j = 0; j < 8; j++) acc[2 * c + (j >> 2)][j & 3] = e[j];
    }

    float mx = -1e30f;
#pragma unroll
    for (int nt = 0; nt < 20; nt++)
#pragma unroll
        for (int r = 0; r < 4; r++) mx = fmaxf(mx, acc[nt][r]);
    mx = fmaxf(mx, __shfl_xor(mx, 16));
    mx = fmaxf(mx, __shfl_xor(mx, 32));
    float sum = 0.f;
#pragma unroll
    for (int nt = 0; nt < 20; nt++)
#pragma unroll
        for (int r = 0; r < 4; r++) { acc[nt][r] = __expf(acc[nt][r] - mx); sum += acc[nt][r]; }
    sum += __shfl_xor(sum, 16);
    sum += __shfl_xor(sum, 32);
    float inv = 1.f / sum;
#pragma unroll
    for (int nt = 0; nt < 20; nt++)
#pragma unroll
        for (int r = 0; r < 4; r++) acc[nt][r] *= inv;

    f32x4 oacc = (f32x4){0.f, 0.f, 0.f, 0.f};
#pragma unroll
    for (int jt2 = 0; jt2 < 10; jt2++) {
        short8 vt = *(const short8*)&sh[5120 + ((jt2 * 4 + quad) * 16 + l16) * 8];
        union { short8 v; uint u[4]; } pf;
        pf.u[0] = pack2(acc[2 * jt2][0], acc[2 * jt2][1]);
        pf.u[1] = pack2(acc[2 * jt2][2], acc[2 * jt2][3]);
        pf.u[2] = pack2(acc[2 * jt2 + 1][0], acc[2 * jt2 + 1][1]);
        pf.u[3] = pack2(acc[2 * jt2 + 1][2], acc[2 * jt2 + 1][3]);
        oacc = __builtin_amdgcn_mfma_f32_16x16x32_bf16(vt, pf.v, oacc, 0, 0, 0);
    }
    us4 ov4 = (us4){f2b(oacc[0]), f2b(oacc[1]), f2b(oacc[2]), f2b(oacc[3])};
    *(us4*)&ao[(b * TOTAL + i0 + wave * 16 + l16) * DM + h * DK + quad * 4] = ov4;
}

// ---------------- head GEMM: MFMA split-K, A = u directly (16 x 81920) ----------------
__global__ __launch_bounds__(256) void k_head(const ushort* __restrict__ u, const ushort* __restrict__ WhT2,
                                              float* __restrict__ acc_head) {
    int t0 = blockIdx.x * 16;
    int wave = threadIdx.x >> 6, lane = threadIdx.x & 63;
    int quad = lane >> 4, l16 = lane & 15;
    int kbeg = (blockIdx.y * 4 + wave) * 1024;
    f32x4 acc = (f32x4){0.f, 0.f, 0.f, 0.f};
    const ushort* za = &u[(size_t)l16 * KHEAD + quad * 8];
    const ushort* wb = &WhT2[(size_t)(t0 + l16) * KHEAD + quad * 8];
#pragma unroll 4
    for (int k = kbeg; k < kbeg + 1024; k += 32) {
        short8 af = *(const short8*)&za[k];
        short8 bf = *(const short8*)&wb[k];
        acc = __builtin_amdgcn_mfma_f32_16x16x32_bf16(af, bf, acc, 0, 0, 0);
    }
#pragma unroll
    for (int r = 0; r < 4; r++)
        atomicAdd(&acc_head[(quad * 4 + r) * TGT + t0 + l16], acc[r]);
}

// ---------------- final ----------------
__global__ void k_final(const float* __restrict__ acc_head, const float* __restrict__ bh,
                        const float* __restrict__ rw, const float* __restrict__ rb,
                        const float* __restrict__ meanv, const float* __restrict__ stdv,
                        float* __restrict__ out) {
    int idx = blockIdx.x * 256 + threadIdx.x;
    if (idx >= NB * TGT) return;
    int bc = idx / TGT, t = idx % TGT, c = bc % C_IN;
    float vv = acc_head[idx] + bh[t];
    vv = (vv - rb[c]) / (rw[c] + EPS * EPS) * stdv[bc] + meanv[bc];
    out[idx] = vv;
}

extern "C" void kernel_launch(void* const* d_in, const int* in_sizes, int n_in,
                              void* d_out, int out_size, void* d_ws, size_t ws_size,
                              hipStream_t stream) {
    const float* z       = (const float*)d_in[0];
    const float* revin_w = (const float*)d_in[1];
    const float* revin_b = (const float*)d_in[2];
    const float* Wf      = (const float*)d_in[3];
    const float* bfv     = (const float*)d_in[4];
    const float* Wc      = (const float*)d_in[5];
    const float* bcv     = (const float*)d_in[6];
    const float* Wpos    = (const float*)d_in[7];
    const float* WQ      = (const float*)d_in[8];
    const float* bQ      = (const float*)d_in[9];
    const float* WK      = (const float*)d_in[10];
    const float* bK      = (const float*)d_in[11];
    const float* WV      = (const float*)d_in[12];
    const float* bV      = (const float*)d_in[13];
    const float* WO      = (const float*)d_in[14];
    const float* bO      = (const float*)d_in[15];
    const float* ln1s    = (const float*)d_in[16];
    const float* ln1b    = (const float*)d_in[17];
    const float* ln2s    = (const float*)d_in[18];
    const float* ln2b    = (const float*)d_in[19];
    const float* F1      = (const float*)d_in[20];
    const float* c1      = (const float*)d_in[21];
    const float* F2      = (const float*)d_in[22];
    const float* c2      = (const float*)d_in[23];
    const float* Wh      = (const float*)d_in[24];
    const float* bh      = (const float*)d_in[25];
    float* out = (float*)d_out;

    char* p = (char*)d_ws;
    float* meanv = (float*)p;    p += 16 * 4;
    float* stdv  = (float*)p;    p += 16 * 4;
    float* acc_head = (float*)p; p += NB * TGT * 4;
    p = (char*)(((size_t)p + 255) & ~255ull);
    float* zn = (float*)p;       p += NB * CTX * 4;
    ushort* u    = (ushort*)p;   p += (size_t)M * DM * 2;
    ushort* qkv  = (ushort*)p;   p += (size_t)3 * M * DM * 2;
    ushort* ax   = (ushort*)p;   p += (size_t)M * DM * 2;
    ushort* hbuf = (ushort*)p;   p += (size_t)M * DFF * 2;
    ushort* Wtqkv = (ushort*)p;  p += (size_t)NL * 768 * 256 * 2;
    ushort* WtO   = (ushort*)p;  p += (size_t)NL * 256 * 256 * 2;
    ushort* Ft1   = (ushort*)p;  p += (size_t)NL * 1024 * 256 * 2;
    ushort* Ft2   = (ushort*)p;  p += (size_t)NL * 256 * 1024 * 2;
    ushort* WhT2  = (ushort*)p;  p += (size_t)TGT * KHEAD * 2;   // 15.7 MB
    p = (char*)(((size_t)p + 255) & ~255ull);
    uint4* sp = (uint4*)p;       p += (size_t)NB * NH * 5 * 10 * 256 * 16;  // 52.4 MB packed bf16 s

    // weight conversions (4 launches)
    k_convt_sq<<<dim3(8, 8, 16), dim3(32, 32), 0, stream>>>(WQ, WK, WV, WO, Wtqkv, WtO);
    k_convt<<<dim3(32, 8, 4), dim3(32, 32), 0, stream>>>(F1, Ft1, 256, 1024, 262144, 262144);
    k_convt<<<dim3(8, 32, 4), dim3(32, 32), 0, stream>>>(F2, Ft2, 1024, 256, 262144, 262144);
    k_convt_head<<<dim3(3, 8, 320), dim3(32, 32), 0, stream>>>(Wh, WhT2);

    k_revin<<<NB, 256, 0, stream>>>(z, revin_w, revin_b, zn, meanv, stdv);
    k_embed<<<NB * TOTAL, 256, 0, stream>>>(zn, Wf, bfv, Wc, bcv, Wpos, u);

    for (int l = 0; l < NL; l++) {
        int mode = (l == 0) ? 0 : (l == NL - 1 ? 2 : 1);
        k_gemm_qkv<<<dim3(M / 64, 3), 256, 0, stream>>>(
            u, Wtqkv + (size_t)l * 768 * 256, bQ + l * DM, bK + l * DM, bV + l * DM, qkv);
        k_attn<<<dim3(NB * NH, 5), 256, 0, stream>>>(qkv, qkv + M * DM, qkv + 2 * M * DM, sp, ax, mode);
        k_gemm_ln<<<M / 64, 256, 0, stream>>>(
            ax, WtO + (size_t)l * 65536, bO + l * DM, ln1s + l * DM, ln1b + l * DM, u, 256);
        k_gemm_gelu<<<dim3(M / 64, 4), 256, 0, stream>>>(
            u, Ft1 + (size_t)l * 262144, c1 + l * DFF, hbuf);
        k_gemm_ln<<<M / 64, 256, 0, stream>>>(
            hbuf, Ft2 + (size_t)l * 262144, c2 + l * DM, ln2s + l * DM, ln2b + l * DM, u, 1024);
    }

    hipMemsetAsync(acc_head, 0, NB * TGT * sizeof(float), stream);
    k_head<<<dim3(TGT / 16, 20), 256, 0, stream>>>(u, WhT2, acc_head);
    k_final<<<(NB * TGT + 255) / 256, 256, 0, stream>>>(acc_head, bh, revin_w, revin_b, meanv, stdv, out);
}

// Round 10
// 498.283 us; speedup vs baseline: 1.3886x; 1.3886x over previous
//
#include <hip/hip_runtime.h>
#include <math.h>

typedef unsigned short ushort;
typedef unsigned int uint;
typedef __attribute__((ext_vector_type(8))) short short8;
typedef __attribute__((ext_vector_type(4))) float f32x4;
typedef __attribute__((ext_vector_type(4))) ushort us4;

constexpr int BS = 2, C_IN = 8, CTX = 1024, TGT = 96;
constexpr int DM = 256, NH = 16, DFF = 1024, NL = 4;
constexpr int NF = 256, TOTAL = 320;
constexpr int NB = 16;
constexpr int DK = 16;
constexpr float EPS = 1e-5f;
constexpr float SCALE = 0.25f;
constexpr int KHEAD = DM * TOTAL;  // 81920
constexpr int M = NB * TOTAL;      // 5120

__device__ __forceinline__ ushort f2b(float x) {
    uint u = __float_as_uint(x);
    u += 0x7fff + ((u >> 16) & 1);
    return (ushort)(u >> 16);
}
__device__ __forceinline__ float bu2f(ushort x) { return __uint_as_float(((uint)x) << 16); }
__device__ __forceinline__ float lo2f(uint p) { return __uint_as_float(p << 16); }
__device__ __forceinline__ float hi2f(uint p) { return __uint_as_float(p & 0xffff0000u); }
__device__ __forceinline__ uint pack2(float a, float b) { return (uint)f2b(a) | ((uint)f2b(b) << 16); }

// ---------------- generic convert+transpose: src fp32 (R x C) -> dst bf16 (C x R) ----------------
__global__ void k_convt(const float* __restrict__ src, ushort* __restrict__ dst,
                        int R, int C, int sls, int dls) {
    __shared__ ushort tile[32][33];
    src += (size_t)blockIdx.z * sls;
    dst += (size_t)blockIdx.z * dls;
    int c0 = blockIdx.x * 32, r0 = blockIdx.y * 32;
    int tx = threadIdx.x, ty = threadIdx.y;
    tile[ty][tx] = f2b(src[(r0 + ty) * C + c0 + tx]);
    __syncthreads();
    dst[(c0 + ty) * R + r0 + tx] = tile[tx][ty];
}

// ---------------- all 16 square (256x256) weights in one launch ----------------
__global__ void k_convt_sq(const float* __restrict__ WQ, const float* __restrict__ WK,
                           const float* __restrict__ WV, const float* __restrict__ WO,
                           ushort* __restrict__ Wtqkv, ushort* __restrict__ WtO) {
    __shared__ ushort tile[32][33];
    int z = blockIdx.z, w = z >> 2, l = z & 3;
    const float* src = (w == 0 ? WQ : (w == 1 ? WK : (w == 2 ? WV : WO))) + l * 65536;
    ushort* dst = (w < 3) ? (Wtqkv + (size_t)l * 768 * 256 + w * 256 * 256)
                          : (WtO + (size_t)l * 65536);
    int c0 = blockIdx.x * 32, r0 = blockIdx.y * 32;
    int tx = threadIdx.x, ty = threadIdx.y;
    tile[ty][tx] = f2b(src[(r0 + ty) * 256 + c0 + tx]);
    __syncthreads();
    dst[(c0 + ty) * 256 + r0 + tx] = tile[tx][ty];
}

// ---------------- head weight permute: WhT2[t][p*256+d] = Wh[(d*320+p)*96 + t] ----------------
__global__ void k_convt_head(const float* __restrict__ Wh, ushort* __restrict__ WhT2) {
    __shared__ ushort tile[32][33];
    int t0 = blockIdx.x * 32, d0 = blockIdx.y * 32, p = blockIdx.z;
    int tx = threadIdx.x, ty = threadIdx.y;
    tile[ty][tx] = f2b(Wh[((size_t)(d0 + ty) * 320 + p) * 96 + t0 + tx]);
    __syncthreads();
    WhT2[(size_t)(t0 + ty) * KHEAD + p * 256 + d0 + tx] = tile[tx][ty];
}

// ---------------- RevIN ----------------
__global__ void k_revin(const float* __restrict__ z, const float* __restrict__ rw,
                        const float* __restrict__ rb, float* __restrict__ zn,
                        float* __restrict__ meanv, float* __restrict__ stdv) {
    int bc = blockIdx.x, t = threadIdx.x;
    __shared__ float r1[256], r2[256];
    float s1 = 0.f, s2 = 0.f;
    for (int i = t; i < CTX; i += 256) {
        float x = z[bc * CTX + i];
        s1 += x; s2 += x * x;
    }
    r1[t] = s1; r2[t] = s2; __syncthreads();
    for (int off = 128; off > 0; off >>= 1) {
        if (t < off) { r1[t] += r1[t + off]; r2[t] += r2[t + off]; }
        __syncthreads();
    }
    float m = r1[0] * (1.0f / CTX);
    float var = r2[0] * (1.0f / CTX) - m * m;
    float sd = sqrtf(var + EPS);
    float w = rw[bc % C_IN], b = rb[bc % C_IN];
    float inv = 1.0f / sd;
    for (int i = t; i < CTX; i += 256) {
        float x = z[bc * CTX + i];
        zn[bc * CTX + i] = (x - m) * inv * w + b;
    }
    if (t == 0) { meanv[bc] = m; stdv[bc] = sd; }
}

// ---------------- dual-scale patch embed + positional -> bf16 u ----------------
__global__ void k_embed(const float* __restrict__ zn, const float* __restrict__ Wf,
                        const float* __restrict__ bfv, const float* __restrict__ Wc,
                        const float* __restrict__ bcv, const float* __restrict__ Wpos,
                        ushort* __restrict__ u) {
    int bc = blockIdx.x / TOTAL, p = blockIdx.x % TOTAL, d = threadIdx.x;
    float acc;
    if (p < NF) {
        acc = bfv[d];
        int base = p * 4;
        for (int i = 0; i < 8; i++) {
            int idx = min(base + i, CTX - 1);
            acc += zn[bc * CTX + idx] * Wf[i * DM + d];
        }
    } else {
        int pc = p - NF;
        acc = bcv[d];
        int base = pc * 16;
        for (int i = 0; i < 32; i++) {
            int idx = min(base + i, CTX - 1);
            acc += zn[bc * CTX + idx] * Wc[i * DM + d];
        }
    }
    acc += Wpos[p * DM + d];
    u[(bc * TOTAL + p) * DM + d] = f2b(acc);
}

// ---------------- bf16 MFMA GEMM: C = A(MxK) @ Wt^T + bias; Wt is (N x K) bf16 ----------------
// 64x64 block tile, 4 waves (proven best balance: 320-960 blocks per dispatch)
template <int GELU, int QKV>
__global__ __launch_bounds__(256) void k_gemm_mfma(const ushort* __restrict__ A,
                                                   const ushort* __restrict__ Wt,
                                                   const float* __restrict__ b0,
                                                   const float* __restrict__ b1,
                                                   const float* __restrict__ b2,
                                                   ushort* __restrict__ C,
                                                   int Mm, int N, int K) {
    __shared__ ushort As[64][40];
    __shared__ ushort Bs[64][40];
    int tid = threadIdx.x;
    int wave = tid >> 6, lane = tid & 63;
    int quad = lane >> 4, l16 = lane & 15;
    int m0 = blockIdx.y * 64, n0 = blockIdx.x * 64;

    f32x4 acc[4];
#pragma unroll
    for (int nt = 0; nt < 4; nt++) acc[nt] = (f32x4){0.f, 0.f, 0.f, 0.f};

    int row = tid >> 2, kc = (tid & 3) * 8;
    for (int k0 = 0; k0 < K; k0 += 32) {
        *(short8*)&As[row][kc] = *(const short8*)&A[(m0 + row) * K + k0 + kc];
        *(short8*)&Bs[row][kc] = *(const short8*)&Wt[(n0 + row) * K + k0 + kc];
        __syncthreads();
        short8 af = *(const short8*)&As[wave * 16 + l16][quad * 8];
#pragma unroll
        for (int nt = 0; nt < 4; nt++) {
            short8 bf = *(const short8*)&Bs[nt * 16 + l16][quad * 8];
            acc[nt] = __builtin_amdgcn_mfma_f32_16x16x32_bf16(af, bf, acc[nt], 0, 0, 0);
        }
        __syncthreads();
    }
#pragma unroll
    for (int nt = 0; nt < 4; nt++) {
        int col = n0 + nt * 16 + l16;
        float bi;
        if (QKV) {
            int bs = (n0 + nt * 16) >> 8;
            const float* bp = bs == 0 ? b0 : (bs == 1 ? b1 : b2);
            bi = bp[col & 255];
        } else {
            bi = b0[col];
        }
#pragma unroll
        for (int r = 0; r < 4; r++) {
            int rowm = m0 + wave * 16 + quad * 4 + r;
            float vv = acc[nt][r] + bi;
            if (GELU) vv = vv * 0.5f * (1.0f + erff(vv * 0.70710678118f));
            if (QKV) C[(col >> 8) * (M * DM) + rowm * DM + (col & 255)] = f2b(vv);
            else C[rowm * N + col] = f2b(vv);
        }
    }
}

// ---------------- MFMA fused attention v4: S^T formulation, quad-aliased K (20.5 KB LDS) ----------------
__global__ __launch_bounds__(256, 4) void k_attn(const ushort* __restrict__ qm, const ushort* __restrict__ km,
                                                 const ushort* __restrict__ vm, uint4* __restrict__ sp,
                                                 ushort* __restrict__ ao, int mode) {
    __shared__ ushort sh[10240];
    uint* sh32 = (uint*)sh;
    int bh = blockIdx.x, b = bh >> 4, h = bh & 15;
    int i0 = blockIdx.y * 64;
    int t = threadIdx.x, wave = t >> 6, lane = t & 63, quad = lane >> 4, l16 = lane & 15;
    const short8 zero8 = (short8){0, 0, 0, 0, 0, 0, 0, 0};

    for (int idx = t; idx < 640; idx += 256) {
        int j = idx >> 1, half = idx & 1;
        short8 kv = *(const short8*)&km[(b * TOTAL + j) * DM + h * DK + half * 8];
        int jt = j >> 4, jl = j & 15;
        *(short8*)&sh[((jt * 2 + half) * 16 + jl) * 8] = kv;
    }
    for (int idx = t; idx < 320; idx += 256) {
        int jp = idx >> 1, dh = idx & 1;
        int j = jp * 2;
        uint4 a = *(const uint4*)&vm[(b * TOTAL + j) * DM + h * DK + dh * 8];
        uint4 bb = *(const uint4*)&vm[(b * TOTAL + j + 1) * DM + h * DK + dh * 8];
        const ushort* ap = (const ushort*)&a;
        const ushort* bp = (const ushort*)&bb;
        int jr = j & 31;
        int q = (jr & 15) >> 2, jj = ((jr >> 4) << 2) + (jr & 3);
        int base = 5120 + ((j >> 5) * 4 + q) * 128 + jj;
#pragma unroll
        for (int dd = 0; dd < 8; dd++) {
            int d = dh * 8 + dd;
            uint val = (uint)ap[dd] | ((uint)bp[dd] << 16);
            sh32[(base + d * 8) >> 1] = val;
        }
    }
    short8 qf = zero8;
    if (quad < 2) qf = *(const short8*)&qm[(b * TOTAL + i0 + wave * 16 + l16) * DM + h * DK + quad * 8];
    __syncthreads();

    f32x4 acc[20];
#pragma unroll
    for (int nt = 0; nt < 20; nt++) {
        short8 kf = *(const short8*)&sh[((nt * 2 + (quad & 1)) * 16 + l16) * 8];
        acc[nt] = __builtin_amdgcn_mfma_f32_16x16x32_bf16(kf, qf, (f32x4){0.f, 0.f, 0.f, 0.f}, 0, 0, 0);
    }

    int cb = (bh * 5 + (int)blockIdx.y) * 10 * 256 + t;
#pragma unroll
    for (int c = 0; c < 10; c++) {
        float e[8];
#pragma unroll
        for (int j = 0; j < 8; j++) e[j] = acc[2 * c + (j >> 2)][j & 3] * SCALE;
        if (mode) {
            uint4 pv = sp[cb + c * 256];
            e[0] += lo2f(pv.x); e[1] += hi2f(pv.x); e[2] += lo2f(pv.y); e[3] += hi2f(pv.y);
            e[4] += lo2f(pv.z); e[5] += hi2f(pv.z); e[6] += lo2f(pv.w); e[7] += hi2f(pv.w);
        }
        if (mode != 2) {
            uint4 ov;
            ov.x = pack2(e[0], e[1]); ov.y = pack2(e[2], e[3]);
            ov.z = pack2(e[4], e[5]); ov.w = pack2(e[6], e[7]);
            sp[cb + c * 256] = ov;
        }
#pragma unroll
        for (int j = 0; j < 8; j++) acc[2 * c + (j >> 2)][j & 3] = e[j];
    }

    float mx = -1e30f;
#pragma unroll
    for (int nt = 0; nt < 20; nt++)
#pragma unroll
        for (int r = 0; r < 4; r++) mx = fmaxf(mx, acc[nt][r]);
    mx = fmaxf(mx, __shfl_xor(mx, 16));
    mx = fmaxf(mx, __shfl_xor(mx, 32));
    float sum = 0.f;
#pragma unroll
    for (int nt = 0; nt < 20; nt++)
#pragma unroll
        for (int r = 0; r < 4; r++) { acc[nt][r] = __expf(acc[nt][r] - mx); sum += acc[nt][r]; }
    sum += __shfl_xor(sum, 16);
    sum += __shfl_xor(sum, 32);
    float inv = 1.f / sum;
#pragma unroll
    for (int nt = 0; nt < 20; nt++)
#pragma unroll
        for (int r = 0; r < 4; r++) acc[nt][r] *= inv;

    f32x4 oacc = (f32x4){0.f, 0.f, 0.f, 0.f};
#pragma unroll
    for (int jt2 = 0; jt2 < 10; jt2++) {
        short8 vt = *(const short8*)&sh[5120 + ((jt2 * 4 + quad) * 16 + l16) * 8];
        union { short8 v; uint u[4]; } pf;
        pf.u[0] = pack2(acc[2 * jt2][0], acc[2 * jt2][1]);
        pf.u[1] = pack2(acc[2 * jt2][2], acc[2 * jt2][3]);
        pf.u[2] = pack2(acc[2 * jt2 + 1][0], acc[2 * jt2 + 1][1]);
        pf.u[3] = pack2(acc[2 * jt2 + 1][2], acc[2 * jt2 + 1][3]);
        oacc = __builtin_amdgcn_mfma_f32_16x16x32_bf16(vt, pf.v, oacc, 0, 0, 0);
    }
    us4 ov4 = (us4){f2b(oacc[0]), f2b(oacc[1]), f2b(oacc[2]), f2b(oacc[3])};
    *(us4*)&ao[(b * TOTAL + i0 + wave * 16 + l16) * DM + h * DK + quad * 4] = ov4;
}

// ---------------- residual add + LayerNorm: wave per row, no LDS/barriers ----------------
__global__ __launch_bounds__(256) void k_add_ln(ushort* __restrict__ u, const ushort* __restrict__ o,
                                                const float* __restrict__ ls, const float* __restrict__ lb) {
    int wave = threadIdx.x >> 6, lane = threadIdx.x & 63;
    int row = blockIdx.x * 4 + wave;
    int d0 = lane * 4;
    uint2 uv = *(const uint2*)&u[row * DM + d0];
    uint2 ov = *(const uint2*)&o[row * DM + d0];
    float x0 = lo2f(uv.x) + lo2f(ov.x);
    float x1 = hi2f(uv.x) + hi2f(ov.x);
    float x2 = lo2f(uv.y) + lo2f(ov.y);
    float x3 = hi2f(uv.y) + hi2f(ov.y);
    float sum = x0 + x1 + x2 + x3;
    float sq = x0 * x0 + x1 * x1 + x2 * x2 + x3 * x3;
#pragma unroll
    for (int off = 1; off < 64; off <<= 1) {
        sum += __shfl_xor(sum, off);
        sq += __shfl_xor(sq, off);
    }
    float m = sum * (1.0f / DM);
    float var = sq * (1.0f / DM) - m * m;
    float rs = rsqrtf(var + EPS);
    f32x4 sc = *(const f32x4*)&ls[d0];
    f32x4 bb = *(const f32x4*)&lb[d0];
    float y0 = (x0 - m) * rs * sc[0] + bb[0];
    float y1 = (x1 - m) * rs * sc[1] + bb[1];
    float y2 = (x2 - m) * rs * sc[2] + bb[2];
    float y3 = (x3 - m) * rs * sc[3] + bb[3];
    uint2 w;
    w.x = pack2(y0, y1); w.y = pack2(y2, y3);
    *(uint2*)&u[row * DM + d0] = w;
}

// ---------------- head GEMM: MFMA split-K, A = u directly (16 x 81920) ----------------
__global__ __launch_bounds__(256) void k_head(const ushort* __restrict__ u, const ushort* __restrict__ WhT2,
                                              float* __restrict__ acc_head) {
    int t0 = blockIdx.x * 16;
    int wave = threadIdx.x >> 6, lane = threadIdx.x & 63;
    int quad = lane >> 4, l16 = lane & 15;
    int kbeg = (blockIdx.y * 4 + wave) * 1024;
    f32x4 acc = (f32x4){0.f, 0.f, 0.f, 0.f};
    const ushort* za = &u[(size_t)l16 * KHEAD + quad * 8];
    const ushort* wb = &WhT2[(size_t)(t0 + l16) * KHEAD + quad * 8];
#pragma unroll 4
    for (int k = kbeg; k < kbeg + 1024; k += 32) {
        short8 af = *(const short8*)&za[k];
        short8 bf = *(const short8*)&wb[k];
        acc = __builtin_amdgcn_mfma_f32_16x16x32_bf16(af, bf, acc, 0, 0, 0);
    }
#pragma unroll
    for (int r = 0; r < 4; r++)
        atomicAdd(&acc_head[(quad * 4 + r) * TGT + t0 + l16], acc[r]);
}

// ---------------- final ----------------
__global__ void k_final(const float* __restrict__ acc_head, const float* __restrict__ bh,
                        const float* __restrict__ rw, const float* __restrict__ rb,
                        const float* __restrict__ meanv, const float* __restrict__ stdv,
                        float* __restrict__ out) {
    int idx = blockIdx.x * 256 + threadIdx.x;
    if (idx >= NB * TGT) return;
    int bc = idx / TGT, t = idx % TGT, c = bc % C_IN;
    float vv = acc_head[idx] + bh[t];
    vv = (vv - rb[c]) / (rw[c] + EPS * EPS) * stdv[bc] + meanv[bc];
    out[idx] = vv;
}

extern "C" void kernel_launch(void* const* d_in, const int* in_sizes, int n_in,
                              void* d_out, int out_size, void* d_ws, size_t ws_size,
                              hipStream_t stream) {
    const float* z       = (const float*)d_in[0];
    const float* revin_w = (const float*)d_in[1];
    const float* revin_b = (const float*)d_in[2];
    const float* Wf      = (const float*)d_in[3];
    const float* bfv     = (const float*)d_in[4];
    const float* Wc      = (const float*)d_in[5];
    const float* bcv     = (const float*)d_in[6];
    const float* Wpos    = (const float*)d_in[7];
    const float* WQ      = (const float*)d_in[8];
    const float* bQ      = (const float*)d_in[9];
    const float* WK      = (const float*)d_in[10];
    const float* bK      = (const float*)d_in[11];
    const float* WV      = (const float*)d_in[12];
    const float* bV      = (const float*)d_in[13];
    const float* WO      = (const float*)d_in[14];
    const float* bO      = (const float*)d_in[15];
    const float* ln1s    = (const float*)d_in[16];
    const float* ln1b    = (const float*)d_in[17];
    const float* ln2s    = (const float*)d_in[18];
    const float* ln2b    = (const float*)d_in[19];
    const float* F1      = (const float*)d_in[20];
    const float* c1      = (const float*)d_in[21];
    const float* F2      = (const float*)d_in[22];
    const float* c2      = (const float*)d_in[23];
    const float* Wh      = (const float*)d_in[24];
    const float* bh      = (const float*)d_in[25];
    float* out = (float*)d_out;

    char* p = (char*)d_ws;
    float* meanv = (float*)p;    p += 16 * 4;
    float* stdv  = (float*)p;    p += 16 * 4;
    float* acc_head = (float*)p; p += NB * TGT * 4;
    p = (char*)(((size_t)p + 255) & ~255ull);
    float* zn = (float*)p;       p += NB * CTX * 4;
    ushort* u    = (ushort*)p;   p += (size_t)M * DM * 2;
    ushort* qkv  = (ushort*)p;   p += (size_t)3 * M * DM * 2;
    ushort* ax   = (ushort*)p;   p += (size_t)M * DM * 2;
    ushort* o    = (ushort*)p;   p += (size_t)M * DM * 2;
    ushort* hbuf = (ushort*)p;   p += (size_t)M * DFF * 2;
    ushort* Wtqkv = (ushort*)p;  p += (size_t)NL * 768 * 256 * 2;
    ushort* WtO   = (ushort*)p;  p += (size_t)NL * 256 * 256 * 2;
    ushort* Ft1   = (ushort*)p;  p += (size_t)NL * 1024 * 256 * 2;
    ushort* Ft2   = (ushort*)p;  p += (size_t)NL * 256 * 1024 * 2;
    ushort* WhT2  = (ushort*)p;  p += (size_t)TGT * KHEAD * 2;   // 15.7 MB
    p = (char*)(((size_t)p + 255) & ~255ull);
    uint4* sp = (uint4*)p;       p += (size_t)NB * NH * 5 * 10 * 256 * 16;  // 52.4 MB packed bf16 s

    // weight conversions (4 launches)
    k_convt_sq<<<dim3(8, 8, 16), dim3(32, 32), 0, stream>>>(WQ, WK, WV, WO, Wtqkv, WtO);
    k_convt<<<dim3(32, 8, 4), dim3(32, 32), 0, stream>>>(F1, Ft1, 256, 1024, 262144, 262144);
    k_convt<<<dim3(8, 32, 4), dim3(32, 32), 0, stream>>>(F2, Ft2, 1024, 256, 262144, 262144);
    k_convt_head<<<dim3(3, 8, 320), dim3(32, 32), 0, stream>>>(Wh, WhT2);

    k_revin<<<NB, 256, 0, stream>>>(z, revin_w, revin_b, zn, meanv, stdv);
    k_embed<<<NB * TOTAL, 256, 0, stream>>>(zn, Wf, bfv, Wc, bcv, Wpos, u);

    for (int l = 0; l < NL; l++) {
        int mode = (l == 0) ? 0 : (l == NL - 1 ? 2 : 1);
        k_gemm_mfma<0, 1><<<dim3(12, 80), 256, 0, stream>>>(
            u, Wtqkv + (size_t)l * 768 * 256, bQ + l * DM, bK + l * DM, bV + l * DM, qkv, M, 768, 256);
        k_attn<<<dim3(NB * NH, 5), 256, 0, stream>>>(qkv, qkv + M * DM, qkv + 2 * M * DM, sp, ax, mode);
        k_gemm_mfma<0, 0><<<dim3(4, 80), 256, 0, stream>>>(
            ax, WtO + (size_t)l * 65536, bO + l * DM, bO + l * DM, bO + l * DM, o, M, 256, 256);
        k_add_ln<<<M / 4, 256, 0, stream>>>(u, o, ln1s + l * DM, ln1b + l * DM);
        k_gemm_mfma<1, 0><<<dim3(16, 80), 256, 0, stream>>>(
            u, Ft1 + (size_t)l * 262144, c1 + l * DFF, c1, c1, hbuf, M, 1024, 256);
        k_gemm_mfma<0, 0><<<dim3(4, 80), 256, 0, stream>>>(
            hbuf, Ft2 + (size_t)l * 262144, c2 + l * DM, c2, c2, o, M, 256, 1024);
        k_add_ln<<<M / 4, 256, 0, stream>>>(u, o, ln2s + l * DM, ln2b + l * DM);
    }

    hipMemsetAsync(acc_head, 0, NB * TGT * sizeof(float), stream);
    k_head<<<dim3(TGT / 16, 20), 256, 0, stream>>>(u, WhT2, acc_head);
    k_final<<<(NB * TGT + 255) / 256, 256, 0, stream>>>(acc_head, bh, revin_w, revin_b, meanv, stdv, out);
}